// Round 18
// baseline (194.542 us; speedup 1.0000x reference)
//
#include <hip/hip_runtime.h>
#include <hip/hip_bf16.h>

typedef __attribute__((ext_vector_type(8))) short s16x8;
typedef __attribute__((ext_vector_type(4))) float f32x4;
typedef __attribute__((ext_vector_type(4))) unsigned int u32x4;

#define BATCH 8
#define NPIX  4096
#define CCH   256
#define RCH   32
#define TK    32              // keys per stream per iteration
#define HALFK 2048
#define NIT   (HALFK / TK)    // 64
#define THR   8.0f
#define LOG2E 1.4426950408889634f
#define XPAD  264             // padded row stride (shorts) for x tiles in LDS

__device__ __forceinline__ unsigned short f2bf(float f) {
  __hip_bfloat16 h = __float2bfloat16(f);
  return __builtin_bit_cast(unsigned short, h);
}

// packed f32x2 -> bf16x2 in one HW instruction (RNE)
__device__ __forceinline__ unsigned int cvt_pk(float lo, float hi) {
  unsigned int r;
  asm("v_cvt_pk_bf16_f32 %0, %1, %2" : "=v"(r) : "v"(lo), "v"(hi));
  return r;
}

__device__ __forceinline__ void gload_lds16(const void* g, void* l) {
  __builtin_amdgcn_global_load_lds(
      (const __attribute__((address_space(1))) void*)g,
      (__attribute__((address_space(3))) void*)l, 16, 0, 0);
}

// ---------------------------------------------------------------------------
// Kernel 0 (tiny): build wqk^T (64x256) and wv^T (256x256) in bf16.
// ---------------------------------------------------------------------------
__global__ void wprep_kernel(const float* __restrict__ wq,
                             const float* __restrict__ wk,
                             const float* __restrict__ wv,
                             unsigned short* __restrict__ wqkT,
                             unsigned short* __restrict__ wvT) {
  int stride = gridDim.x * blockDim.x;
  int i0 = blockIdx.x * blockDim.x + threadIdx.x;
  for (int i = i0; i < 64 * CCH; i += stride) {
    int d = i >> 8, c = i & 255;
    float v = (d < RCH) ? wq[c * RCH + d] : wk[c * RCH + (d - RCH)];
    wqkT[i] = f2bf(v);
  }
  for (int i = i0; i < CCH * CCH; i += stride) {
    int d = i >> 8, c = i & 255;
    wvT[i] = f2bf(wv[c * CCH + d]);
  }
}

// ---------------------------------------------------------------------------
// Kernel 1 (fused, cast-fused): blocks 0..511 q,k projection; blocks
// 512..2559 v projection. Each block stages its own 64x256 x-tile in
// padded LDS (bf16), converting once per element (R17, BW-floor).
// ---------------------------------------------------------------------------
__global__ __launch_bounds__(256)
void proj_kernel(const float* __restrict__ x,
                 const unsigned short* __restrict__ wqkT,
                 const unsigned short* __restrict__ wvT,
                 const float* __restrict__ bq,
                 const float* __restrict__ bk,
                 const float* __restrict__ bv,
                 unsigned short* __restrict__ qb,
                 unsigned short* __restrict__ kb,
                 unsigned short* __restrict__ vT) {
  __shared__ __attribute__((aligned(16))) unsigned short Xt[64 * XPAD];

  int t = threadIdx.x;
  int w = t >> 6, l = t & 63, g = l >> 4, lc = l & 15;
  f32x4 zero = {0.f, 0.f, 0.f, 0.f};

  if (blockIdx.x < 512) {
    int row0 = blockIdx.x * 64;
    #pragma unroll
    for (int i = 0; i < 16; ++i) {
      int flat4 = i * 256 + t;
      int row = flat4 >> 6, col4 = flat4 & 63;
      float4 v = *reinterpret_cast<const float4*>(
          x + ((size_t)(row0 + row)) * CCH + col4 * 4);
      ushort4 o4;
      o4.x = f2bf(v.x); o4.y = f2bf(v.y); o4.z = f2bf(v.z); o4.w = f2bf(v.w);
      *reinterpret_cast<ushort4*>(&Xt[row * XPAD + col4 * 4]) = o4;
    }
    __syncthreads();

    f32x4 acc[4];
    for (int ct = 0; ct < 4; ++ct) acc[ct] = zero;
    for (int ks = 0; ks < 8; ++ks) {
      s16x8 a = *reinterpret_cast<const s16x8*>(
          &Xt[(w * 16 + lc) * XPAD + ks * 32 + g * 8]);
      for (int ct = 0; ct < 4; ++ct) {
        s16x8 bfr = *reinterpret_cast<const s16x8*>(
            wqkT + (size_t)(ct * 16 + lc) * CCH + ks * 32 + g * 8);
        acc[ct] = __builtin_amdgcn_mfma_f32_16x16x32_bf16(a, bfr, acc[ct], 0, 0, 0);
      }
    }
    for (int ct = 0; ct < 4; ++ct) {
      int col = ct * 16 + lc;
      float bias = (col < RCH) ? bq[col] : bk[col - RCH];
      for (int r = 0; r < 4; ++r) {
        int row = row0 + w * 16 + 4 * g + r;
        float v = fmaxf(acc[ct][r] + bias, 0.f);
        if (col < RCH) qb[(size_t)row * RCH + col] = f2bf(v * LOG2E);
        else           kb[(size_t)row * RCH + (col - RCH)] = f2bf(v);
      }
    }
  } else {
    int idx = blockIdx.x - 512;
    int b = idx & 7; idx >>= 3;
    int dt = idx & 3; int nt = idx >> 2;
    int d0 = dt * 64 + w * 16;
    int n0 = nt * 64;
    #pragma unroll
    for (int i = 0; i < 16; ++i) {
      int flat4 = i * 256 + t;
      int row = flat4 >> 6, col4 = flat4 & 63;
      float4 v = *reinterpret_cast<const float4*>(
          x + ((size_t)b * NPIX + n0 + row) * CCH + col4 * 4);
      ushort4 o4;
      o4.x = f2bf(v.x); o4.y = f2bf(v.y); o4.z = f2bf(v.z); o4.w = f2bf(v.w);
      *reinterpret_cast<ushort4*>(&Xt[row * XPAD + col4 * 4]) = o4;
    }
    __syncthreads();

    f32x4 acc[4];
    for (int ct = 0; ct < 4; ++ct) acc[ct] = zero;
    for (int ks = 0; ks < 8; ++ks) {
      s16x8 a = *reinterpret_cast<const s16x8*>(
          wvT + (size_t)(d0 + lc) * CCH + ks * 32 + g * 8);
      for (int ct = 0; ct < 4; ++ct) {
        s16x8 bfr = *reinterpret_cast<const s16x8*>(
            &Xt[(ct * 16 + lc) * XPAD + ks * 32 + g * 8]);
        acc[ct] = __builtin_amdgcn_mfma_f32_16x16x32_bf16(a, bfr, acc[ct], 0, 0, 0);
      }
    }
    for (int ct = 0; ct < 4; ++ct) {
      for (int r = 0; r < 4; ++r) {
        int d = d0 + 4 * g + r;
        int n = n0 + ct * 16 + lc;
        vT[((size_t)b * CCH + d) * NPIX + n] = f2bf(acc[ct][r] + bv[d]);
      }
    }
  }
}

// ---------------------------------------------------------------------------
// Kernel 2: flash attention + residual. OCCUPANCY variant:
// Grid 1024 = 8 batches x 128 q-tiles of 32 q. Block = 4 waves (2 pairs),
// each wave 16 q x 256 ch (O = 64 VGPR), wave s handles key stream s.
// Vlds SINGLE-buffered 32KB -> ~33KB/block -> 4 blocks/CU = 4 waves/SIMD.
// Per iter: [lgkm0+bar] DMA(8, current tile) | QK (global K, reg) |
// wrapped K-prefetch | softmax | vmcnt(2) counted | bar | PV(16 rd+MFMA).
// lsum via ones-MFMA; cvt_pk; max3; exp2; defer-max THR=8; exact pair
// merge via Vlds alias at the end.
// ---------------------------------------------------------------------------
__global__ __launch_bounds__(256, 4)
void attn_kernel(const unsigned short* __restrict__ qb,
                 const unsigned short* __restrict__ kb,
                 const unsigned short* __restrict__ vT,
                 const float* __restrict__ x,
                 float* __restrict__ out) {
  __shared__ __attribute__((aligned(16))) unsigned short Vlds[CCH * 64];
  __shared__ __attribute__((aligned(16))) float mergeLS[2][16];  // [a][q]
  __shared__ float mLds[2];                                      // donor m

  int b  = blockIdx.x & 7;         // batch == XCD -> vT/K/Q L2-resident
  int qt = blockIdx.x >> 3;        // 0..127
  int t  = threadIdx.x;
  int w = t >> 6, l = t & 63, g = l >> 4, lc = l & 15;
  int a = w >> 1, s = w & 1;
  const size_t bN = (size_t)b * NPIX;
  f32x4 zero = {0.f, 0.f, 0.f, 0.f};

  const unsigned short* kbase = kb + bN * RCH;
  const unsigned short* vbase = vT + (size_t)b * CCH * NPIX;

  // Q fragment (B-operand): q = qbase + lc
  int qbase = qt * 32 + a * 16;
  s16x8 qf = *reinterpret_cast<const s16x8*>(qb + (bN + qbase + lc) * RCH + g * 8);

  // staging: thread covers ch=(t>>3)+32i, LDS granule gr=t&7 (linear dest);
  // source granule pre-swizzled; granules 0-3 = stream0, 4-7 = stream1.
  int chb = t >> 3, gr = t & 7;
  int gsw = gr ^ (chb & 7);
  int koff = (gsw < 4) ? (gsw * 8) : (HALFK + (gsw - 4) * 8);
  const unsigned short* vsrc = vbase + (size_t)chb * NPIX + koff;

  // K pre-permuted rows
  int krb = 8 * (lc >> 2) + (lc & 3);
  int kO  = s * HALFK + krb;

  // PV read byte offset within a 128B row (this wave's stream granules)
  unsigned int swz = (lc & 7) << 4;
  int vrS = (s * 64 + g * 16) ^ swz;

  // ones B-operand for lsum MFMA (bf16 1.0 = 0x3F80)
  s16x8 ones;
  #pragma unroll
  for (int i = 0; i < 8; ++i) ones[i] = (short)0x3F80;

  f32x4 o[16];
  #pragma unroll
  for (int cc = 0; cc < 16; ++cc) o[cc] = zero;
  f32x4 ols = zero;
  float m = -1e30f;

  // prologue: K subtile 0
  s16x8 kf0 = *reinterpret_cast<const s16x8*>(kbase + (size_t)(kO + 0) * RCH + g * 8);
  s16x8 kf1 = *reinterpret_cast<const s16x8*>(kbase + (size_t)(kO + 4) * RCH + g * 8);

  for (int it = 0; it < NIT; ++it) {
    int kv = it * TK;

    // ---- barrier #1: all PV reads of previous tile landed ----
    asm volatile("s_waitcnt lgkmcnt(0)" ::: "memory");
    __builtin_amdgcn_s_barrier();
    asm volatile("" ::: "memory");

    // ---- DMA-stage CURRENT tile (both streams), then pin order ----
    #pragma unroll
    for (int i = 0; i < 8; ++i)
      gload_lds16(vsrc + kv + (size_t)i * 32 * NPIX,
                  (char*)&Vlds[0] + i * 4096 + t * 16);
    __builtin_amdgcn_sched_barrier(0);

    // ---- QK^T (S^T in PV-ready key order) ----
    f32x4 s0 = __builtin_amdgcn_mfma_f32_16x16x32_bf16(kf0, qf, zero, 0, 0, 0);
    f32x4 s1 = __builtin_amdgcn_mfma_f32_16x16x32_bf16(kf1, qf, zero, 0, 0, 0);

    // K prefetch for next iter (wrapped on last: harmless reload of tile 0)
    {
      int kv2 = (kv + TK) & (HALFK - 1);
      kf0 = *reinterpret_cast<const s16x8*>(
          kbase + (size_t)(kO + kv2 + 0) * RCH + g * 8);
      kf1 = *reinterpret_cast<const s16x8*>(
          kbase + (size_t)(kO + kv2 + 4) * RCH + g * 8);
    }

    // ---- softmax (wave-global max over 16 q, deferred) ----
    float xA = fmaxf(fmaxf(s0[0], s0[1]), fmaxf(s0[2], s0[3]));
    float xB = fmaxf(fmaxf(s1[0], s1[1]), fmaxf(s1[2], s1[3]));
    float pmax = fmaxf(xA, xB);

    float sc = 1.f;
    int resc = !__all(pmax - m <= THR);
    if (resc) {
      #pragma unroll
      for (int off = 1; off <= 32; off <<= 1)
        pmax = fmaxf(pmax, __shfl_xor(pmax, off));
      float mnew = fmaxf(m, pmax);
      sc = exp2f(m - mnew);
      m = mnew;
    }

    unsigned int pk0 = cvt_pk(exp2f(s0[0] - m), exp2f(s0[1] - m));
    unsigned int pk1 = cvt_pk(exp2f(s0[2] - m), exp2f(s0[3] - m));
    unsigned int pk2 = cvt_pk(exp2f(s1[0] - m), exp2f(s1[1] - m));
    unsigned int pk3 = cvt_pk(exp2f(s1[2] - m), exp2f(s1[3] - m));
    u32x4 ua = {pk0, pk1, pk2, pk3};
    s16x8 pa = __builtin_bit_cast(s16x8, ua);

    if (resc) {
      #pragma unroll
      for (int cc = 0; cc < 16; ++cc)
        #pragma unroll
        for (int r = 0; r < 4; ++r) o[cc][r] *= sc;
      #pragma unroll
      for (int r = 0; r < 4; ++r) ols[r] *= sc;
    }

    // lsum MFMA (no Vlds dependency)
    ols = __builtin_amdgcn_mfma_f32_16x16x32_bf16(pa, ones, ols, 0, 0, 0);

    // ---- counted wait: drain the 8 DMA, leave 2 K-prefetch in flight ----
    asm volatile("s_waitcnt vmcnt(2)" ::: "memory");
    __builtin_amdgcn_s_barrier();
    asm volatile("" ::: "memory");

    // ---- PV: 16 reads + 16 MFMA ----
    const char* pb = (const char*)&Vlds[0] + lc * 128 + vrS;
    __builtin_amdgcn_s_setprio(1);
    #pragma unroll
    for (int cc = 0; cc < 16; ++cc) {
      s16x8 vb = *reinterpret_cast<const s16x8*>(pb + cc * 2048);
      o[cc] = __builtin_amdgcn_mfma_f32_16x16x32_bf16(pa, vb, o[cc], 0, 0, 0);
    }
    __builtin_amdgcn_s_setprio(0);
  }

  // ---- merge prep: donor publishes per-q lsum (layout q=4g+r) + m ----
  if (s == 1) {
    if (lc == 0)
      *reinterpret_cast<f32x4*>(&mergeLS[a][4 * g]) = ols;
    if (l == 0) mLds[a] = m;
  }
  __syncthreads();   // all PV done -> Vlds reusable as merge buffer

  float* mrg = (float*)&Vlds[0];     // 2 donors x 4096 floats = 32KB
  if (s == 1) {
    float* base = mrg + a * 4096 + l * 64;
    #pragma unroll
    for (int cc = 0; cc < 16; ++cc)
      *reinterpret_cast<f32x4*>(base + ((cc + l) & 15) * 4) = o[cc];
  }
  __syncthreads();
  if (s == 0) {
    float mB = mLds[a];
    float mT = fmaxf(m, mB);
    float sAc = exp2f(m - mT), sBc = exp2f(mB - mT);
    const float* base = mrg + a * 4096 + l * 64;
    f32x4 lB4 = *reinterpret_cast<const f32x4*>(&mergeLS[a][4 * g]);
    f32x4 rl;
    #pragma unroll
    for (int r = 0; r < 4; ++r)
      rl[r] = 1.0f / (ols[r] * sAc + lB4[r] * sBc);
    #pragma unroll
    for (int cc = 0; cc < 16; ++cc) {
      f32x4 ob = *reinterpret_cast<const f32x4*>(base + ((cc + l) & 15) * 4);
      #pragma unroll
      for (int r = 0; r < 4; ++r) {
        size_t row = bN + qbase + 4 * g + r;
        size_t oi = row * CCH + cc * 16 + lc;
        out[oi] = (o[cc][r] * sAc + ob[r] * sBc) * rl[r] + x[oi];
      }
    }
  }
}

// ---------------------------------------------------------------------------
extern "C" void kernel_launch(void* const* d_in, const int* in_sizes, int n_in,
                              void* d_out, int out_size, void* d_ws, size_t ws_size,
                              hipStream_t stream) {
  const float* x  = (const float*)d_in[0];
  const float* wq = (const float*)d_in[1];
  const float* bq = (const float*)d_in[2];
  const float* wk = (const float*)d_in[3];
  const float* bk = (const float*)d_in[4];
  const float* wv = (const float*)d_in[5];
  const float* bv = (const float*)d_in[6];
  float* out = (float*)d_out;

  unsigned short* ws   = (unsigned short*)d_ws;
  unsigned short* qb   = ws;                   // 8*4096*32  = 1,048,576
  unsigned short* kb   = qb + 1048576;         // 1,048,576
  unsigned short* vT   = kb + 1048576;         // 8*256*4096 = 8,388,608
  unsigned short* wqkT = vT + 8388608;         // 64*256 = 16,384
  unsigned short* wvT  = wqkT + 16384;         // 256*256 = 65,536

  wprep_kernel<<<dim3(80), dim3(256), 0, stream>>>(wq, wk, wv, wqkT, wvT);
  proj_kernel<<<dim3(2560), dim3(256), 0, stream>>>(x, wqkT, wvT, bq, bk, bv,
                                                    qb, kb, vT);
  attn_kernel<<<dim3(1024), dim3(256), 0, stream>>>(qb, kb, vT, x, out);
}

// Round 19
// 139.577 us; speedup vs baseline: 1.3938x; 1.3938x over previous
//
#include <hip/hip_runtime.h>
#include <hip/hip_bf16.h>

typedef __attribute__((ext_vector_type(8))) short s16x8;
typedef __attribute__((ext_vector_type(4))) float f32x4;
typedef __attribute__((ext_vector_type(4))) unsigned int u32x4;

#define BATCH 8
#define NPIX  4096
#define CCH   256
#define RCH   32
#define TK    32              // keys per stream per iteration
#define HALFK 2048
#define NIT   (HALFK / TK)    // 64
#define THR   8.0f
#define LOG2E 1.4426950408889634f
#define XPAD  264             // padded row stride (shorts) for x tiles in LDS

__device__ __forceinline__ unsigned short f2bf(float f) {
  __hip_bfloat16 h = __float2bfloat16(f);
  return __builtin_bit_cast(unsigned short, h);
}

// packed f32x2 -> bf16x2 in one HW instruction (RNE)
__device__ __forceinline__ unsigned int cvt_pk(float lo, float hi) {
  unsigned int r;
  asm("v_cvt_pk_bf16_f32 %0, %1, %2" : "=v"(r) : "v"(lo), "v"(hi));
  return r;
}

__device__ __forceinline__ void gload_lds16(const void* g, void* l) {
  __builtin_amdgcn_global_load_lds(
      (const __attribute__((address_space(1))) void*)g,
      (__attribute__((address_space(3))) void*)l, 16, 0, 0);
}

// ---------------------------------------------------------------------------
// Kernel 0 (tiny): build wqk^T (64x256) and wv^T (256x256) in bf16.
// ---------------------------------------------------------------------------
__global__ void wprep_kernel(const float* __restrict__ wq,
                             const float* __restrict__ wk,
                             const float* __restrict__ wv,
                             unsigned short* __restrict__ wqkT,
                             unsigned short* __restrict__ wvT) {
  int stride = gridDim.x * blockDim.x;
  int i0 = blockIdx.x * blockDim.x + threadIdx.x;
  for (int i = i0; i < 64 * CCH; i += stride) {
    int d = i >> 8, c = i & 255;
    float v = (d < RCH) ? wq[c * RCH + d] : wk[c * RCH + (d - RCH)];
    wqkT[i] = f2bf(v);
  }
  for (int i = i0; i < CCH * CCH; i += stride) {
    int d = i >> 8, c = i & 255;
    wvT[i] = f2bf(wv[c * CCH + d]);
  }
}

// ---------------------------------------------------------------------------
// Kernel 1 (fused, cast-fused): blocks 0..511 q,k projection; blocks
// 512..2559 v projection. Each block stages its own 64x256 x-tile in
// padded LDS (bf16), converting once per element (BW-floor).
// ---------------------------------------------------------------------------
__global__ __launch_bounds__(256)
void proj_kernel(const float* __restrict__ x,
                 const unsigned short* __restrict__ wqkT,
                 const unsigned short* __restrict__ wvT,
                 const float* __restrict__ bq,
                 const float* __restrict__ bk,
                 const float* __restrict__ bv,
                 unsigned short* __restrict__ qb,
                 unsigned short* __restrict__ kb,
                 unsigned short* __restrict__ vT) {
  __shared__ __attribute__((aligned(16))) unsigned short Xt[64 * XPAD];

  int t = threadIdx.x;
  int w = t >> 6, l = t & 63, g = l >> 4, lc = l & 15;
  f32x4 zero = {0.f, 0.f, 0.f, 0.f};

  if (blockIdx.x < 512) {
    int row0 = blockIdx.x * 64;
    #pragma unroll
    for (int i = 0; i < 16; ++i) {
      int flat4 = i * 256 + t;
      int row = flat4 >> 6, col4 = flat4 & 63;
      float4 v = *reinterpret_cast<const float4*>(
          x + ((size_t)(row0 + row)) * CCH + col4 * 4);
      ushort4 o4;
      o4.x = f2bf(v.x); o4.y = f2bf(v.y); o4.z = f2bf(v.z); o4.w = f2bf(v.w);
      *reinterpret_cast<ushort4*>(&Xt[row * XPAD + col4 * 4]) = o4;
    }
    __syncthreads();

    f32x4 acc[4];
    for (int ct = 0; ct < 4; ++ct) acc[ct] = zero;
    for (int ks = 0; ks < 8; ++ks) {
      s16x8 a = *reinterpret_cast<const s16x8*>(
          &Xt[(w * 16 + lc) * XPAD + ks * 32 + g * 8]);
      for (int ct = 0; ct < 4; ++ct) {
        s16x8 bfr = *reinterpret_cast<const s16x8*>(
            wqkT + (size_t)(ct * 16 + lc) * CCH + ks * 32 + g * 8);
        acc[ct] = __builtin_amdgcn_mfma_f32_16x16x32_bf16(a, bfr, acc[ct], 0, 0, 0);
      }
    }
    for (int ct = 0; ct < 4; ++ct) {
      int col = ct * 16 + lc;
      float bias = (col < RCH) ? bq[col] : bk[col - RCH];
      for (int r = 0; r < 4; ++r) {
        int row = row0 + w * 16 + 4 * g + r;
        float v = fmaxf(acc[ct][r] + bias, 0.f);
        if (col < RCH) qb[(size_t)row * RCH + col] = f2bf(v * LOG2E);
        else           kb[(size_t)row * RCH + (col - RCH)] = f2bf(v);
      }
    }
  } else {
    int idx = blockIdx.x - 512;
    int b = idx & 7; idx >>= 3;
    int dt = idx & 3; int nt = idx >> 2;
    int d0 = dt * 64 + w * 16;
    int n0 = nt * 64;
    #pragma unroll
    for (int i = 0; i < 16; ++i) {
      int flat4 = i * 256 + t;
      int row = flat4 >> 6, col4 = flat4 & 63;
      float4 v = *reinterpret_cast<const float4*>(
          x + ((size_t)b * NPIX + n0 + row) * CCH + col4 * 4);
      ushort4 o4;
      o4.x = f2bf(v.x); o4.y = f2bf(v.y); o4.z = f2bf(v.z); o4.w = f2bf(v.w);
      *reinterpret_cast<ushort4*>(&Xt[row * XPAD + col4 * 4]) = o4;
    }
    __syncthreads();

    f32x4 acc[4];
    for (int ct = 0; ct < 4; ++ct) acc[ct] = zero;
    for (int ks = 0; ks < 8; ++ks) {
      s16x8 a = *reinterpret_cast<const s16x8*>(
          wvT + (size_t)(d0 + lc) * CCH + ks * 32 + g * 8);
      for (int ct = 0; ct < 4; ++ct) {
        s16x8 bfr = *reinterpret_cast<const s16x8*>(
            &Xt[(ct * 16 + lc) * XPAD + ks * 32 + g * 8]);
        acc[ct] = __builtin_amdgcn_mfma_f32_16x16x32_bf16(a, bfr, acc[ct], 0, 0, 0);
      }
    }
    for (int ct = 0; ct < 4; ++ct) {
      for (int r = 0; r < 4; ++r) {
        int d = d0 + 4 * g + r;
        int n = n0 + ct * 16 + lc;
        vT[((size_t)b * CCH + d) * NPIX + n] = f2bf(acc[ct][r] + bv[d]);
      }
    }
  }
}

// ---------------------------------------------------------------------------
// Kernel 2: flash attention + residual. R12/R16/R17 structure (best
// measured). Block = 1 batch x 64 queries, 4 waves (2 pairs), grid 512.
//   Pair a: q [qt*64+a*32, +32). Wave s=w&1 handles key stream s (2048 keys,
//   TK=32/iter) with its own online softmax (wave-global m over 32 q).
//   - V staged interleaved via global_load_lds (pre-swizzled source),
//     double-buffered, ONE __syncthreads per iter.
//   - one ds_read V fragment feeds both q-groups' MFMAs (2x reuse).
//   - lsum via ones-MFMA (lands as lsum[q=4g+r], no shuffles).
//   - cvt_pk asm for P->bf16; max3-nested fmax; exp2 domain; defer-max THR=8.
//   - End: exact flash merge per pair via Vlds alias; s=0 writes output.
// ---------------------------------------------------------------------------
__global__ __launch_bounds__(256, 2)
void attn_kernel(const unsigned short* __restrict__ qb,
                 const unsigned short* __restrict__ kb,
                 const unsigned short* __restrict__ vT,
                 const float* __restrict__ x,
                 float* __restrict__ out) {
  __shared__ __attribute__((aligned(16))) unsigned short Vlds[2][CCH * 64];
  __shared__ __attribute__((aligned(16))) float mergeLS[2][32];  // [a][q]
  __shared__ float mLds[2];                                      // donor m

  int b  = blockIdx.x & 7;         // batch == XCD -> vT/K/Q L2-resident
  int qt = blockIdx.x >> 3;        // 0..63
  int t  = threadIdx.x;
  int w = t >> 6, l = t & 63, g = l >> 4, lc = l & 15;
  int a = w >> 1, s = w & 1;
  const size_t bN = (size_t)b * NPIX;
  f32x4 zero = {0.f, 0.f, 0.f, 0.f};

  const unsigned short* kbase = kb + bN * RCH;
  const unsigned short* vbase = vT + (size_t)b * CCH * NPIX;

  // two Q fragments (B-operand): q = qbase+lc and qbase+16+lc
  int qbase = qt * 64 + a * 32;
  s16x8 qfA = *reinterpret_cast<const s16x8*>(qb + (bN + qbase + lc) * RCH + g * 8);
  s16x8 qfB = *reinterpret_cast<const s16x8*>(qb + (bN + qbase + 16 + lc) * RCH + g * 8);

  // staging: thread covers ch=(t>>3)+32i, LDS granule gr=t&7 (linear dest);
  // source granule pre-swizzled; granules 0-3 = stream0, 4-7 = stream1.
  int chb = t >> 3, gr = t & 7;
  int gsw = gr ^ (chb & 7);
  int koff = (gsw < 4) ? (gsw * 8) : (HALFK + (gsw - 4) * 8);
  const unsigned short* vsrc = vbase + (size_t)chb * NPIX + koff;

  // K pre-permuted rows
  int krb = 8 * (lc >> 2) + (lc & 3);
  int kO  = s * HALFK + krb;

  // PV read byte offset within a 128B row (this wave's stream granules)
  unsigned int swz = (lc & 7) << 4;
  int vrS = (s * 64 + g * 16) ^ swz;

  // ones B-operand for lsum MFMA (bf16 1.0 = 0x3F80)
  s16x8 ones;
  #pragma unroll
  for (int i = 0; i < 8; ++i) ones[i] = (short)0x3F80;

  f32x4 o[2][16];
  #pragma unroll
  for (int qh = 0; qh < 2; ++qh)
    #pragma unroll
    for (int cc = 0; cc < 16; ++cc) o[qh][cc] = zero;
  f32x4 ols[2];
  ols[0] = zero; ols[1] = zero;
  float m = -1e30f;

  // ---- prologue: stage iter 0, load K subtile 0 ----
  #pragma unroll
  for (int i = 0; i < 8; ++i)
    gload_lds16(vsrc + (size_t)i * 32 * NPIX,
                (char*)&Vlds[0][0] + i * 4096 + t * 16);
  s16x8 kf0 = *reinterpret_cast<const s16x8*>(kbase + (size_t)(kO + 0) * RCH + g * 8);
  s16x8 kf1 = *reinterpret_cast<const s16x8*>(kbase + (size_t)(kO + 4) * RCH + g * 8);
  __syncthreads();

  for (int it = 0; it < NIT; ++it) {
    int p = it & 1;
    int kv = it * TK;
    bool nx = (it + 1) < NIT;

    // stage next iteration's subtiles (both streams) into the other buffer
    if (nx) {
      #pragma unroll
      for (int i = 0; i < 8; ++i)
        gload_lds16(vsrc + kv + TK + (size_t)i * 32 * NPIX,
                    (char*)&Vlds[p ^ 1][0] + i * 4096 + t * 16);
    }

    // ---- QK^T for both q-groups (S^T in PV-ready key order) ----
    f32x4 sA0 = __builtin_amdgcn_mfma_f32_16x16x32_bf16(kf0, qfA, zero, 0, 0, 0);
    f32x4 sA1 = __builtin_amdgcn_mfma_f32_16x16x32_bf16(kf1, qfA, zero, 0, 0, 0);
    f32x4 sB0 = __builtin_amdgcn_mfma_f32_16x16x32_bf16(kf0, qfB, zero, 0, 0, 0);
    f32x4 sB1 = __builtin_amdgcn_mfma_f32_16x16x32_bf16(kf1, qfB, zero, 0, 0, 0);

    // prefetch next K subtile
    if (nx) {
      kf0 = *reinterpret_cast<const s16x8*>(
          kbase + (size_t)(kO + kv + TK + 0) * RCH + g * 8);
      kf1 = *reinterpret_cast<const s16x8*>(
          kbase + (size_t)(kO + kv + TK + 4) * RCH + g * 8);
    }

    // ---- softmax max (triple-nested fmax -> v_max3) ----
    float xA = fmaxf(fmaxf(sA0[0], sA0[1]), fmaxf(sA0[2], sA0[3]));
    float xB = fmaxf(fmaxf(sA1[0], sA1[1]), fmaxf(sA1[2], sA1[3]));
    float xC = fmaxf(fmaxf(sB0[0], sB0[1]), fmaxf(sB0[2], sB0[3]));
    float xD = fmaxf(fmaxf(sB1[0], sB1[1]), fmaxf(sB1[2], sB1[3]));
    float pmax = fmaxf(fmaxf(xA, xB), fmaxf(xC, xD));

    float sc = 1.f;
    int resc = !__all(pmax - m <= THR);
    if (resc) {
      #pragma unroll
      for (int off = 1; off <= 32; off <<= 1)
        pmax = fmaxf(pmax, __shfl_xor(pmax, off));
      float mnew = fmaxf(m, pmax);
      sc = exp2f(m - mnew);
      m = mnew;
    }

    // ---- exps + packed bf16 (cvt_pk) ----
    unsigned int pkA[4], pkB[4];
    pkA[0] = cvt_pk(exp2f(sA0[0] - m), exp2f(sA0[1] - m));
    pkA[1] = cvt_pk(exp2f(sA0[2] - m), exp2f(sA0[3] - m));
    pkA[2] = cvt_pk(exp2f(sA1[0] - m), exp2f(sA1[1] - m));
    pkA[3] = cvt_pk(exp2f(sA1[2] - m), exp2f(sA1[3] - m));
    pkB[0] = cvt_pk(exp2f(sB0[0] - m), exp2f(sB0[1] - m));
    pkB[1] = cvt_pk(exp2f(sB0[2] - m), exp2f(sB0[3] - m));
    pkB[2] = cvt_pk(exp2f(sB1[0] - m), exp2f(sB1[1] - m));
    pkB[3] = cvt_pk(exp2f(sB1[2] - m), exp2f(sB1[3] - m));

    if (resc) {
      #pragma unroll
      for (int qh = 0; qh < 2; ++qh) {
        #pragma unroll
        for (int cc = 0; cc < 16; ++cc)
          #pragma unroll
          for (int r = 0; r < 4; ++r) o[qh][cc][r] *= sc;
        #pragma unroll
        for (int r = 0; r < 4; ++r) ols[qh][r] *= sc;
      }
    }

    // ---- PV: one V fragment feeds both q-groups; +lsum MFMA vs ones ----
    u32x4 uA = {pkA[0], pkA[1], pkA[2], pkA[3]};
    u32x4 uB = {pkB[0], pkB[1], pkB[2], pkB[3]};
    s16x8 paA = __builtin_bit_cast(s16x8, uA);
    s16x8 paB = __builtin_bit_cast(s16x8, uB);
    const char* pb = (const char*)&Vlds[p][0] + lc * 128 + vrS;
    __builtin_amdgcn_s_setprio(1);
    ols[0] = __builtin_amdgcn_mfma_f32_16x16x32_bf16(paA, ones, ols[0], 0, 0, 0);
    ols[1] = __builtin_amdgcn_mfma_f32_16x16x32_bf16(paB, ones, ols[1], 0, 0, 0);
    #pragma unroll
    for (int cc = 0; cc < 16; ++cc) {
      s16x8 vb = *reinterpret_cast<const s16x8*>(pb + cc * 2048);
      o[0][cc] = __builtin_amdgcn_mfma_f32_16x16x32_bf16(paA, vb, o[0][cc], 0, 0, 0);
      o[1][cc] = __builtin_amdgcn_mfma_f32_16x16x32_bf16(paB, vb, o[1][cc], 0, 0, 0);
    }
    __builtin_amdgcn_s_setprio(0);

    __syncthreads();
  }

  // ---- merge prep: donor publishes per-q lsum (layout q = 4g+r) + m ----
  if (s == 1) {
    if (lc == 0) {
      *reinterpret_cast<f32x4*>(&mergeLS[a][4 * g])      = ols[0];
      *reinterpret_cast<f32x4*>(&mergeLS[a][16 + 4 * g]) = ols[1];
    }
    if (l == 0) mLds[a] = m;
  }
  __syncthreads();   // all PV done -> Vlds reusable as merge buffer

  float* mrg = (float*)&Vlds[0][0];   // 2 donors x 8192 floats
  if (s == 1) {
    float* base = mrg + a * 8192 + l * 128;
    #pragma unroll
    for (int qh = 0; qh < 2; ++qh)
      #pragma unroll
      for (int cc = 0; cc < 16; ++cc) {
        int idx = qh * 16 + cc;
        *reinterpret_cast<f32x4*>(base + ((idx + l) & 31) * 4) = o[qh][cc];
      }
  }
  __syncthreads();
  if (s == 0) {
    float mB = mLds[a];
    float mT = fmaxf(m, mB);
    float sAc = exp2f(m - mT), sBc = exp2f(mB - mT);
    const float* base = mrg + a * 8192 + l * 128;
    #pragma unroll
    for (int qh = 0; qh < 2; ++qh) {
      f32x4 lB4 = *reinterpret_cast<const f32x4*>(&mergeLS[a][qh * 16 + 4 * g]);
      f32x4 rl;
      #pragma unroll
      for (int r = 0; r < 4; ++r)
        rl[r] = 1.0f / (ols[qh][r] * sAc + lB4[r] * sBc);
      #pragma unroll
      for (int cc = 0; cc < 16; ++cc) {
        int idx = qh * 16 + cc;
        f32x4 ob = *reinterpret_cast<const f32x4*>(base + ((idx + l) & 31) * 4);
        #pragma unroll
        for (int r = 0; r < 4; ++r) {
          size_t row = bN + qbase + qh * 16 + 4 * g + r;
          size_t oi = row * CCH + cc * 16 + lc;
          out[oi] = (o[qh][cc][r] * sAc + ob[r] * sBc) * rl[r] + x[oi];
        }
      }
    }
  }
}

// ---------------------------------------------------------------------------
extern "C" void kernel_launch(void* const* d_in, const int* in_sizes, int n_in,
                              void* d_out, int out_size, void* d_ws, size_t ws_size,
                              hipStream_t stream) {
  const float* x  = (const float*)d_in[0];
  const float* wq = (const float*)d_in[1];
  const float* bq = (const float*)d_in[2];
  const float* wk = (const float*)d_in[3];
  const float* bk = (const float*)d_in[4];
  const float* wv = (const float*)d_in[5];
  const float* bv = (const float*)d_in[6];
  float* out = (float*)d_out;

  unsigned short* ws   = (unsigned short*)d_ws;
  unsigned short* qb   = ws;                   // 8*4096*32  = 1,048,576
  unsigned short* kb   = qb + 1048576;         // 1,048,576
  unsigned short* vT   = kb + 1048576;         // 8*256*4096 = 8,388,608
  unsigned short* wqkT = vT + 8388608;         // 64*256 = 16,384
  unsigned short* wvT  = wqkT + 16384;         // 256*256 = 65,536

  wprep_kernel<<<dim3(80), dim3(256), 0, stream>>>(wq, wk, wv, wqkT, wvT);
  proj_kernel<<<dim3(2560), dim3(256), 0, stream>>>(x, wqkT, wvT, bq, bk, bv,
                                                    qb, kb, vT);
  attn_kernel<<<dim3(512), dim3(256), 0, stream>>>(qb, kb, vT, x, out);
}

// Round 20
// 136.906 us; speedup vs baseline: 1.4210x; 1.0195x over previous
//
#include <hip/hip_runtime.h>
#include <hip/hip_bf16.h>

typedef __attribute__((ext_vector_type(8))) short s16x8;
typedef __attribute__((ext_vector_type(4))) float f32x4;
typedef __attribute__((ext_vector_type(4))) unsigned int u32x4;

#define BATCH 8
#define NPIX  4096
#define CCH   256
#define RCH   32
#define TK    32              // keys per stream per iteration
#define HALFK 2048
#define NIT   (HALFK / TK)    // 64
#define THR   8.0f
#define LOG2E 1.4426950408889634f
#define XPAD  264             // padded row stride (shorts) for LDS tiles

__device__ __forceinline__ unsigned short f2bf(float f) {
  __hip_bfloat16 h = __float2bfloat16(f);
  return __builtin_bit_cast(unsigned short, h);
}

// packed f32x2 -> bf16x2 in one HW instruction (RNE)
__device__ __forceinline__ unsigned int cvt_pk(float lo, float hi) {
  unsigned int r;
  asm("v_cvt_pk_bf16_f32 %0, %1, %2" : "=v"(r) : "v"(lo), "v"(hi));
  return r;
}

__device__ __forceinline__ void gload_lds16(const void* g, void* l) {
  __builtin_amdgcn_global_load_lds(
      (const __attribute__((address_space(1))) void*)g,
      (__attribute__((address_space(3))) void*)l, 16, 0, 0);
}

// ---------------------------------------------------------------------------
// Kernel 0 (fused proj, weight-conversion inline — no separate wprep):
// blocks 0..511: q,k projection (relu; q scaled by log2e). Each block stages
//   x-tile (64x256 -> bf16 Xt) AND wqk^T (64x256 -> bf16 Wt) in padded LDS.
// blocks 512..2559: v projection into transposed vT[b][d][n]. Each block
//   stages x-tile AND its 64-row wv^T slice.
// All conversions once per element per block, outside the MFMA loop.
// ---------------------------------------------------------------------------
__global__ __launch_bounds__(256)
void proj_kernel(const float* __restrict__ x,
                 const float* __restrict__ wq,
                 const float* __restrict__ wk,
                 const float* __restrict__ wv,
                 const float* __restrict__ bq,
                 const float* __restrict__ bk,
                 const float* __restrict__ bv,
                 unsigned short* __restrict__ qb,
                 unsigned short* __restrict__ kb,
                 unsigned short* __restrict__ vT) {
  __shared__ __attribute__((aligned(16))) unsigned short Xt[64 * XPAD];
  __shared__ __attribute__((aligned(16))) unsigned short Wt[64 * XPAD];

  int t = threadIdx.x;
  int w = t >> 6, l = t & 63, g = l >> 4, lc = l & 15;
  f32x4 zero = {0.f, 0.f, 0.f, 0.f};

  if (blockIdx.x < 512) {
    // ---------------- q,k projection ----------------
    int row0 = blockIdx.x * 64;
    // stage x tile
    #pragma unroll
    for (int i = 0; i < 16; ++i) {
      int flat4 = i * 256 + t;
      int row = flat4 >> 6, col4 = flat4 & 63;
      float4 v = *reinterpret_cast<const float4*>(
          x + ((size_t)(row0 + row)) * CCH + col4 * 4);
      ushort4 o4;
      o4.x = f2bf(v.x); o4.y = f2bf(v.y); o4.z = f2bf(v.z); o4.w = f2bf(v.w);
      *reinterpret_cast<ushort4*>(&Xt[row * XPAD + col4 * 4]) = o4;
    }
    // stage wqk^T: Wt[d][c], d<32 from wq, else wk (transposed convert)
    #pragma unroll
    for (int i = 0; i < 8; ++i) {
      int f = i * 256 + t;
      int c = f >> 3, d4 = f & 7;
      float4 vq = *reinterpret_cast<const float4*>(wq + (size_t)c * RCH + 4 * d4);
      Wt[(4 * d4 + 0) * XPAD + c] = f2bf(vq.x);
      Wt[(4 * d4 + 1) * XPAD + c] = f2bf(vq.y);
      Wt[(4 * d4 + 2) * XPAD + c] = f2bf(vq.z);
      Wt[(4 * d4 + 3) * XPAD + c] = f2bf(vq.w);
      float4 vk = *reinterpret_cast<const float4*>(wk + (size_t)c * RCH + 4 * d4);
      Wt[(32 + 4 * d4 + 0) * XPAD + c] = f2bf(vk.x);
      Wt[(32 + 4 * d4 + 1) * XPAD + c] = f2bf(vk.y);
      Wt[(32 + 4 * d4 + 2) * XPAD + c] = f2bf(vk.z);
      Wt[(32 + 4 * d4 + 3) * XPAD + c] = f2bf(vk.w);
    }
    __syncthreads();

    f32x4 acc[4];
    for (int ct = 0; ct < 4; ++ct) acc[ct] = zero;
    for (int ks = 0; ks < 8; ++ks) {
      s16x8 a = *reinterpret_cast<const s16x8*>(
          &Xt[(w * 16 + lc) * XPAD + ks * 32 + g * 8]);
      for (int ct = 0; ct < 4; ++ct) {
        s16x8 bfr = *reinterpret_cast<const s16x8*>(
            &Wt[(ct * 16 + lc) * XPAD + ks * 32 + g * 8]);
        acc[ct] = __builtin_amdgcn_mfma_f32_16x16x32_bf16(a, bfr, acc[ct], 0, 0, 0);
      }
    }
    for (int ct = 0; ct < 4; ++ct) {
      int col = ct * 16 + lc;
      float bias = (col < RCH) ? bq[col] : bk[col - RCH];
      for (int r = 0; r < 4; ++r) {
        int row = row0 + w * 16 + 4 * g + r;
        float v = fmaxf(acc[ct][r] + bias, 0.f);
        if (col < RCH) qb[(size_t)row * RCH + col] = f2bf(v * LOG2E);
        else           kb[(size_t)row * RCH + (col - RCH)] = f2bf(v);
      }
    }
  } else {
    // ---------------- v projection ----------------
    int idx = blockIdx.x - 512;
    int b = idx & 7; idx >>= 3;
    int dt = idx & 3; int nt = idx >> 2;
    int d0 = dt * 64 + w * 16;
    int n0 = nt * 64;
    // stage x tile
    #pragma unroll
    for (int i = 0; i < 16; ++i) {
      int flat4 = i * 256 + t;
      int row = flat4 >> 6, col4 = flat4 & 63;
      float4 v = *reinterpret_cast<const float4*>(
          x + ((size_t)b * NPIX + n0 + row) * CCH + col4 * 4);
      ushort4 o4;
      o4.x = f2bf(v.x); o4.y = f2bf(v.y); o4.z = f2bf(v.z); o4.w = f2bf(v.w);
      *reinterpret_cast<ushort4*>(&Xt[row * XPAD + col4 * 4]) = o4;
    }
    // stage wv^T slice: Wt[dd][c] = wv[c][dt*64+dd]
    #pragma unroll
    for (int i = 0; i < 16; ++i) {
      int f = i * 256 + t;
      int c = f >> 4, d4 = f & 15;
      float4 v = *reinterpret_cast<const float4*>(
          wv + (size_t)c * CCH + dt * 64 + 4 * d4);
      Wt[(4 * d4 + 0) * XPAD + c] = f2bf(v.x);
      Wt[(4 * d4 + 1) * XPAD + c] = f2bf(v.y);
      Wt[(4 * d4 + 2) * XPAD + c] = f2bf(v.z);
      Wt[(4 * d4 + 3) * XPAD + c] = f2bf(v.w);
    }
    __syncthreads();

    f32x4 acc[4];
    for (int ct = 0; ct < 4; ++ct) acc[ct] = zero;
    for (int ks = 0; ks < 8; ++ks) {
      s16x8 a = *reinterpret_cast<const s16x8*>(
          &Wt[(w * 16 + lc) * XPAD + ks * 32 + g * 8]);
      for (int ct = 0; ct < 4; ++ct) {
        s16x8 bfr = *reinterpret_cast<const s16x8*>(
            &Xt[(ct * 16 + lc) * XPAD + ks * 32 + g * 8]);
        acc[ct] = __builtin_amdgcn_mfma_f32_16x16x32_bf16(a, bfr, acc[ct], 0, 0, 0);
      }
    }
    for (int ct = 0; ct < 4; ++ct) {
      for (int r = 0; r < 4; ++r) {
        int d = d0 + 4 * g + r;
        int n = n0 + ct * 16 + lc;
        vT[((size_t)b * CCH + d) * NPIX + n] = f2bf(acc[ct][r] + bv[d]);
      }
    }
  }
}

// ---------------------------------------------------------------------------
// Kernel 1: flash attention + residual. R12/R16/R17 structure (best
// measured). Block = 1 batch x 64 queries, 4 waves (2 pairs), grid 512.
//   Pair a: q [qt*64+a*32, +32). Wave s=w&1 handles key stream s (2048 keys,
//   TK=32/iter) with its own online softmax (wave-global m over 32 q).
//   - V staged interleaved via global_load_lds (pre-swizzled source),
//     double-buffered, ONE __syncthreads per iter.
//   - one ds_read V fragment feeds both q-groups' MFMAs (2x reuse).
//   - lsum via ones-MFMA (lands as lsum[q=4g+r], no shuffles).
//   - cvt_pk asm for P->bf16; max3-nested fmax; exp2 domain; defer-max THR=8.
//   - End: exact flash merge per pair via Vlds alias; s=0 writes output.
// ---------------------------------------------------------------------------
__global__ __launch_bounds__(256, 2)
void attn_kernel(const unsigned short* __restrict__ qb,
                 const unsigned short* __restrict__ kb,
                 const unsigned short* __restrict__ vT,
                 const float* __restrict__ x,
                 float* __restrict__ out) {
  __shared__ __attribute__((aligned(16))) unsigned short Vlds[2][CCH * 64];
  __shared__ __attribute__((aligned(16))) float mergeLS[2][32];  // [a][q]
  __shared__ float mLds[2];                                      // donor m

  int b  = blockIdx.x & 7;         // batch == XCD -> vT/K/Q L2-resident
  int qt = blockIdx.x >> 3;        // 0..63
  int t  = threadIdx.x;
  int w = t >> 6, l = t & 63, g = l >> 4, lc = l & 15;
  int a = w >> 1, s = w & 1;
  const size_t bN = (size_t)b * NPIX;
  f32x4 zero = {0.f, 0.f, 0.f, 0.f};

  const unsigned short* kbase = kb + bN * RCH;
  const unsigned short* vbase = vT + (size_t)b * CCH * NPIX;

  // two Q fragments (B-operand): q = qbase+lc and qbase+16+lc
  int qbase = qt * 64 + a * 32;
  s16x8 qfA = *reinterpret_cast<const s16x8*>(qb + (bN + qbase + lc) * RCH + g * 8);
  s16x8 qfB = *reinterpret_cast<const s16x8*>(qb + (bN + qbase + 16 + lc) * RCH + g * 8);

  // staging: thread covers ch=(t>>3)+32i, LDS granule gr=t&7 (linear dest);
  // source granule pre-swizzled; granules 0-3 = stream0, 4-7 = stream1.
  int chb = t >> 3, gr = t & 7;
  int gsw = gr ^ (chb & 7);
  int koff = (gsw < 4) ? (gsw * 8) : (HALFK + (gsw - 4) * 8);
  const unsigned short* vsrc = vbase + (size_t)chb * NPIX + koff;

  // K pre-permuted rows
  int krb = 8 * (lc >> 2) + (lc & 3);
  int kO  = s * HALFK + krb;

  // PV read byte offset within a 128B row (this wave's stream granules)
  unsigned int swz = (lc & 7) << 4;
  int vrS = (s * 64 + g * 16) ^ swz;

  // ones B-operand for lsum MFMA (bf16 1.0 = 0x3F80)
  s16x8 ones;
  #pragma unroll
  for (int i = 0; i < 8; ++i) ones[i] = (short)0x3F80;

  f32x4 o[2][16];
  #pragma unroll
  for (int qh = 0; qh < 2; ++qh)
    #pragma unroll
    for (int cc = 0; cc < 16; ++cc) o[qh][cc] = zero;
  f32x4 ols[2];
  ols[0] = zero; ols[1] = zero;
  float m = -1e30f;

  // ---- prologue: stage iter 0, load K subtile 0 ----
  #pragma unroll
  for (int i = 0; i < 8; ++i)
    gload_lds16(vsrc + (size_t)i * 32 * NPIX,
                (char*)&Vlds[0][0] + i * 4096 + t * 16);
  s16x8 kf0 = *reinterpret_cast<const s16x8*>(kbase + (size_t)(kO + 0) * RCH + g * 8);
  s16x8 kf1 = *reinterpret_cast<const s16x8*>(kbase + (size_t)(kO + 4) * RCH + g * 8);
  __syncthreads();

  for (int it = 0; it < NIT; ++it) {
    int p = it & 1;
    int kv = it * TK;
    bool nx = (it + 1) < NIT;

    // stage next iteration's subtiles (both streams) into the other buffer
    if (nx) {
      #pragma unroll
      for (int i = 0; i < 8; ++i)
        gload_lds16(vsrc + kv + TK + (size_t)i * 32 * NPIX,
                    (char*)&Vlds[p ^ 1][0] + i * 4096 + t * 16);
    }

    // ---- QK^T for both q-groups (S^T in PV-ready key order) ----
    f32x4 sA0 = __builtin_amdgcn_mfma_f32_16x16x32_bf16(kf0, qfA, zero, 0, 0, 0);
    f32x4 sA1 = __builtin_amdgcn_mfma_f32_16x16x32_bf16(kf1, qfA, zero, 0, 0, 0);
    f32x4 sB0 = __builtin_amdgcn_mfma_f32_16x16x32_bf16(kf0, qfB, zero, 0, 0, 0);
    f32x4 sB1 = __builtin_amdgcn_mfma_f32_16x16x32_bf16(kf1, qfB, zero, 0, 0, 0);

    // prefetch next K subtile
    if (nx) {
      kf0 = *reinterpret_cast<const s16x8*>(
          kbase + (size_t)(kO + kv + TK + 0) * RCH + g * 8);
      kf1 = *reinterpret_cast<const s16x8*>(
          kbase + (size_t)(kO + kv + TK + 4) * RCH + g * 8);
    }

    // ---- softmax max (triple-nested fmax -> v_max3) ----
    float xA = fmaxf(fmaxf(sA0[0], sA0[1]), fmaxf(sA0[2], sA0[3]));
    float xB = fmaxf(fmaxf(sA1[0], sA1[1]), fmaxf(sA1[2], sA1[3]));
    float xC = fmaxf(fmaxf(sB0[0], sB0[1]), fmaxf(sB0[2], sB0[3]));
    float xD = fmaxf(fmaxf(sB1[0], sB1[1]), fmaxf(sB1[2], sB1[3]));
    float pmax = fmaxf(fmaxf(xA, xB), fmaxf(xC, xD));

    float sc = 1.f;
    int resc = !__all(pmax - m <= THR);
    if (resc) {
      #pragma unroll
      for (int off = 1; off <= 32; off <<= 1)
        pmax = fmaxf(pmax, __shfl_xor(pmax, off));
      float mnew = fmaxf(m, pmax);
      sc = exp2f(m - mnew);
      m = mnew;
    }

    // ---- exps + packed bf16 (cvt_pk) ----
    unsigned int pkA[4], pkB[4];
    pkA[0] = cvt_pk(exp2f(sA0[0] - m), exp2f(sA0[1] - m));
    pkA[1] = cvt_pk(exp2f(sA0[2] - m), exp2f(sA0[3] - m));
    pkA[2] = cvt_pk(exp2f(sA1[0] - m), exp2f(sA1[1] - m));
    pkA[3] = cvt_pk(exp2f(sA1[2] - m), exp2f(sA1[3] - m));
    pkB[0] = cvt_pk(exp2f(sB0[0] - m), exp2f(sB0[1] - m));
    pkB[1] = cvt_pk(exp2f(sB0[2] - m), exp2f(sB0[3] - m));
    pkB[2] = cvt_pk(exp2f(sB1[0] - m), exp2f(sB1[1] - m));
    pkB[3] = cvt_pk(exp2f(sB1[2] - m), exp2f(sB1[3] - m));

    if (resc) {
      #pragma unroll
      for (int qh = 0; qh < 2; ++qh) {
        #pragma unroll
        for (int cc = 0; cc < 16; ++cc)
          #pragma unroll
          for (int r = 0; r < 4; ++r) o[qh][cc][r] *= sc;
        #pragma unroll
        for (int r = 0; r < 4; ++r) ols[qh][r] *= sc;
      }
    }

    // ---- PV: one V fragment feeds both q-groups; +lsum MFMA vs ones ----
    u32x4 uA = {pkA[0], pkA[1], pkA[2], pkA[3]};
    u32x4 uB = {pkB[0], pkB[1], pkB[2], pkB[3]};
    s16x8 paA = __builtin_bit_cast(s16x8, uA);
    s16x8 paB = __builtin_bit_cast(s16x8, uB);
    const char* pb = (const char*)&Vlds[p][0] + lc * 128 + vrS;
    __builtin_amdgcn_s_setprio(1);
    ols[0] = __builtin_amdgcn_mfma_f32_16x16x32_bf16(paA, ones, ols[0], 0, 0, 0);
    ols[1] = __builtin_amdgcn_mfma_f32_16x16x32_bf16(paB, ones, ols[1], 0, 0, 0);
    #pragma unroll
    for (int cc = 0; cc < 16; ++cc) {
      s16x8 vb = *reinterpret_cast<const s16x8*>(pb + cc * 2048);
      o[0][cc] = __builtin_amdgcn_mfma_f32_16x16x32_bf16(paA, vb, o[0][cc], 0, 0, 0);
      o[1][cc] = __builtin_amdgcn_mfma_f32_16x16x32_bf16(paB, vb, o[1][cc], 0, 0, 0);
    }
    __builtin_amdgcn_s_setprio(0);

    __syncthreads();
  }

  // ---- merge prep: donor publishes per-q lsum (layout q = 4g+r) + m ----
  if (s == 1) {
    if (lc == 0) {
      *reinterpret_cast<f32x4*>(&mergeLS[a][4 * g])      = ols[0];
      *reinterpret_cast<f32x4*>(&mergeLS[a][16 + 4 * g]) = ols[1];
    }
    if (l == 0) mLds[a] = m;
  }
  __syncthreads();   // all PV done -> Vlds reusable as merge buffer

  float* mrg = (float*)&Vlds[0][0];   // 2 donors x 8192 floats
  if (s == 1) {
    float* base = mrg + a * 8192 + l * 128;
    #pragma unroll
    for (int qh = 0; qh < 2; ++qh)
      #pragma unroll
      for (int cc = 0; cc < 16; ++cc) {
        int idx = qh * 16 + cc;
        *reinterpret_cast<f32x4*>(base + ((idx + l) & 31) * 4) = o[qh][cc];
      }
  }
  __syncthreads();
  if (s == 0) {
    float mB = mLds[a];
    float mT = fmaxf(m, mB);
    float sAc = exp2f(m - mT), sBc = exp2f(mB - mT);
    const float* base = mrg + a * 8192 + l * 128;
    #pragma unroll
    for (int qh = 0; qh < 2; ++qh) {
      f32x4 lB4 = *reinterpret_cast<const f32x4*>(&mergeLS[a][qh * 16 + 4 * g]);
      f32x4 rl;
      #pragma unroll
      for (int r = 0; r < 4; ++r)
        rl[r] = 1.0f / (ols[qh][r] * sAc + lB4[r] * sBc);
      #pragma unroll
      for (int cc = 0; cc < 16; ++cc) {
        int idx = qh * 16 + cc;
        f32x4 ob = *reinterpret_cast<const f32x4*>(base + ((idx + l) & 31) * 4);
        #pragma unroll
        for (int r = 0; r < 4; ++r) {
          size_t row = bN + qbase + qh * 16 + 4 * g + r;
          size_t oi = row * CCH + cc * 16 + lc;
          out[oi] = (o[qh][cc][r] * sAc + ob[r] * sBc) * rl[r] + x[oi];
        }
      }
    }
  }
}

// ---------------------------------------------------------------------------
extern "C" void kernel_launch(void* const* d_in, const int* in_sizes, int n_in,
                              void* d_out, int out_size, void* d_ws, size_t ws_size,
                              hipStream_t stream) {
  const float* x  = (const float*)d_in[0];
  const float* wq = (const float*)d_in[1];
  const float* bq = (const float*)d_in[2];
  const float* wk = (const float*)d_in[3];
  const float* bk = (const float*)d_in[4];
  const float* wv = (const float*)d_in[5];
  const float* bv = (const float*)d_in[6];
  float* out = (float*)d_out;

  unsigned short* ws = (unsigned short*)d_ws;
  unsigned short* qb = ws;                   // 8*4096*32  = 1,048,576
  unsigned short* kb = qb + 1048576;         // 1,048,576
  unsigned short* vT = kb + 1048576;         // 8*256*4096 = 8,388,608

  proj_kernel<<<dim3(2560), dim3(256), 0, stream>>>(x, wq, wk, wv, bq, bk, bv,
                                                    qb, kb, vT);
  attn_kernel<<<dim3(512), dim3(256), 0, stream>>>(qb, kb, vT, x, out);
}

// Round 21
// 135.911 us; speedup vs baseline: 1.4314x; 1.0073x over previous
//
#include <hip/hip_runtime.h>
#include <hip/hip_bf16.h>

typedef __attribute__((ext_vector_type(8))) short s16x8;
typedef __attribute__((ext_vector_type(4))) float f32x4;
typedef __attribute__((ext_vector_type(4))) unsigned int u32x4;

#define BATCH 8
#define NPIX  4096
#define CCH   256
#define RCH   32
#define TK    32              // keys per stream per iteration
#define HALFK 2048
#define NIT   (HALFK / TK)    // 64
#define THR   8.0f
#define LOG2E 1.4426950408889634f
#define XPAD  264             // padded row stride (shorts) for LDS tiles

__device__ __forceinline__ unsigned short f2bf(float f) {
  __hip_bfloat16 h = __float2bfloat16(f);
  return __builtin_bit_cast(unsigned short, h);
}

// packed f32x2 -> bf16x2 in one HW instruction (RNE)
__device__ __forceinline__ unsigned int cvt_pk(float lo, float hi) {
  unsigned int r;
  asm("v_cvt_pk_bf16_f32 %0, %1, %2" : "=v"(r) : "v"(lo), "v"(hi));
  return r;
}

__device__ __forceinline__ void gload_lds16(const void* g, void* l) {
  __builtin_amdgcn_global_load_lds(
      (const __attribute__((address_space(1))) void*)g,
      (__attribute__((address_space(3))) void*)l, 16, 0, 0);
}

// ---------------------------------------------------------------------------
// Kernel 0 (fused proj, weight-conversion inline):
// blocks 0..511: q,k projection (relu; q scaled by log2e); stages x-tile and
// wqk^T in padded LDS. blocks 512..2559: v projection into vT[b][d][n];
// stages x-tile and its 64-row wv^T slice. Conversions once per element.
// ---------------------------------------------------------------------------
__global__ __launch_bounds__(256)
void proj_kernel(const float* __restrict__ x,
                 const float* __restrict__ wq,
                 const float* __restrict__ wk,
                 const float* __restrict__ wv,
                 const float* __restrict__ bq,
                 const float* __restrict__ bk,
                 const float* __restrict__ bv,
                 unsigned short* __restrict__ qb,
                 unsigned short* __restrict__ kb,
                 unsigned short* __restrict__ vT) {
  __shared__ __attribute__((aligned(16))) unsigned short Xt[64 * XPAD];
  __shared__ __attribute__((aligned(16))) unsigned short Wt[64 * XPAD];

  int t = threadIdx.x;
  int w = t >> 6, l = t & 63, g = l >> 4, lc = l & 15;
  f32x4 zero = {0.f, 0.f, 0.f, 0.f};

  if (blockIdx.x < 512) {
    // ---------------- q,k projection ----------------
    int row0 = blockIdx.x * 64;
    #pragma unroll
    for (int i = 0; i < 16; ++i) {
      int flat4 = i * 256 + t;
      int row = flat4 >> 6, col4 = flat4 & 63;
      float4 v = *reinterpret_cast<const float4*>(
          x + ((size_t)(row0 + row)) * CCH + col4 * 4);
      ushort4 o4;
      o4.x = f2bf(v.x); o4.y = f2bf(v.y); o4.z = f2bf(v.z); o4.w = f2bf(v.w);
      *reinterpret_cast<ushort4*>(&Xt[row * XPAD + col4 * 4]) = o4;
    }
    #pragma unroll
    for (int i = 0; i < 8; ++i) {
      int f = i * 256 + t;
      int c = f >> 3, d4 = f & 7;
      float4 vq = *reinterpret_cast<const float4*>(wq + (size_t)c * RCH + 4 * d4);
      Wt[(4 * d4 + 0) * XPAD + c] = f2bf(vq.x);
      Wt[(4 * d4 + 1) * XPAD + c] = f2bf(vq.y);
      Wt[(4 * d4 + 2) * XPAD + c] = f2bf(vq.z);
      Wt[(4 * d4 + 3) * XPAD + c] = f2bf(vq.w);
      float4 vk = *reinterpret_cast<const float4*>(wk + (size_t)c * RCH + 4 * d4);
      Wt[(32 + 4 * d4 + 0) * XPAD + c] = f2bf(vk.x);
      Wt[(32 + 4 * d4 + 1) * XPAD + c] = f2bf(vk.y);
      Wt[(32 + 4 * d4 + 2) * XPAD + c] = f2bf(vk.z);
      Wt[(32 + 4 * d4 + 3) * XPAD + c] = f2bf(vk.w);
    }
    __syncthreads();

    f32x4 acc[4];
    for (int ct = 0; ct < 4; ++ct) acc[ct] = zero;
    for (int ks = 0; ks < 8; ++ks) {
      s16x8 a = *reinterpret_cast<const s16x8*>(
          &Xt[(w * 16 + lc) * XPAD + ks * 32 + g * 8]);
      for (int ct = 0; ct < 4; ++ct) {
        s16x8 bfr = *reinterpret_cast<const s16x8*>(
            &Wt[(ct * 16 + lc) * XPAD + ks * 32 + g * 8]);
        acc[ct] = __builtin_amdgcn_mfma_f32_16x16x32_bf16(a, bfr, acc[ct], 0, 0, 0);
      }
    }
    for (int ct = 0; ct < 4; ++ct) {
      int col = ct * 16 + lc;
      float bias = (col < RCH) ? bq[col] : bk[col - RCH];
      for (int r = 0; r < 4; ++r) {
        int row = row0 + w * 16 + 4 * g + r;
        float v = fmaxf(acc[ct][r] + bias, 0.f);
        if (col < RCH) qb[(size_t)row * RCH + col] = f2bf(v * LOG2E);
        else           kb[(size_t)row * RCH + (col - RCH)] = f2bf(v);
      }
    }
  } else {
    // ---------------- v projection ----------------
    int idx = blockIdx.x - 512;
    int b = idx & 7; idx >>= 3;
    int dt = idx & 3; int nt = idx >> 2;
    int d0 = dt * 64 + w * 16;
    int n0 = nt * 64;
    #pragma unroll
    for (int i = 0; i < 16; ++i) {
      int flat4 = i * 256 + t;
      int row = flat4 >> 6, col4 = flat4 & 63;
      float4 v = *reinterpret_cast<const float4*>(
          x + ((size_t)b * NPIX + n0 + row) * CCH + col4 * 4);
      ushort4 o4;
      o4.x = f2bf(v.x); o4.y = f2bf(v.y); o4.z = f2bf(v.z); o4.w = f2bf(v.w);
      *reinterpret_cast<ushort4*>(&Xt[row * XPAD + col4 * 4]) = o4;
    }
    #pragma unroll
    for (int i = 0; i < 16; ++i) {
      int f = i * 256 + t;
      int c = f >> 4, d4 = f & 15;
      float4 v = *reinterpret_cast<const float4*>(
          wv + (size_t)c * CCH + dt * 64 + 4 * d4);
      Wt[(4 * d4 + 0) * XPAD + c] = f2bf(v.x);
      Wt[(4 * d4 + 1) * XPAD + c] = f2bf(v.y);
      Wt[(4 * d4 + 2) * XPAD + c] = f2bf(v.z);
      Wt[(4 * d4 + 3) * XPAD + c] = f2bf(v.w);
    }
    __syncthreads();

    f32x4 acc[4];
    for (int ct = 0; ct < 4; ++ct) acc[ct] = zero;
    for (int ks = 0; ks < 8; ++ks) {
      s16x8 a = *reinterpret_cast<const s16x8*>(
          &Wt[(w * 16 + lc) * XPAD + ks * 32 + g * 8]);
      for (int ct = 0; ct < 4; ++ct) {
        s16x8 bfr = *reinterpret_cast<const s16x8*>(
            &Xt[(ct * 16 + lc) * XPAD + ks * 32 + g * 8]);
        acc[ct] = __builtin_amdgcn_mfma_f32_16x16x32_bf16(a, bfr, acc[ct], 0, 0, 0);
      }
    }
    for (int ct = 0; ct < 4; ++ct) {
      for (int r = 0; r < 4; ++r) {
        int d = d0 + 4 * g + r;
        int n = n0 + ct * 16 + lc;
        vT[((size_t)b * CCH + d) * NPIX + n] = f2bf(acc[ct][r] + bv[d]);
      }
    }
  }
}

// ---------------------------------------------------------------------------
// Kernel 1: flash attention + residual. R12/R17/R20 structure + -m FOLD:
// QK MFMA C-operand = splat(-m), so S arrives pre-shifted and the exps need
// no per-element subtraction (16 v_sub/iter/wave removed). Valid since
// relu'd q,k => S >= 0 => m init 0 is a true lower bound. On the rare
// rescale, delta is subtracted from the 16 live s values + mneg updated.
// All else identical to R20 (best measured).
// ---------------------------------------------------------------------------
__global__ __launch_bounds__(256, 2)
void attn_kernel(const unsigned short* __restrict__ qb,
                 const unsigned short* __restrict__ kb,
                 const unsigned short* __restrict__ vT,
                 const float* __restrict__ x,
                 float* __restrict__ out) {
  __shared__ __attribute__((aligned(16))) unsigned short Vlds[2][CCH * 64];
  __shared__ __attribute__((aligned(16))) float mergeLS[2][32];  // [a][q]
  __shared__ float mLds[2];                                      // donor m

  int b  = blockIdx.x & 7;         // batch == XCD -> vT/K/Q L2-resident
  int qt = blockIdx.x >> 3;        // 0..63
  int t  = threadIdx.x;
  int w = t >> 6, l = t & 63, g = l >> 4, lc = l & 15;
  int a = w >> 1, s = w & 1;
  const size_t bN = (size_t)b * NPIX;
  f32x4 zero = {0.f, 0.f, 0.f, 0.f};

  const unsigned short* kbase = kb + bN * RCH;
  const unsigned short* vbase = vT + (size_t)b * CCH * NPIX;

  // two Q fragments (B-operand): q = qbase+lc and qbase+16+lc
  int qbase = qt * 64 + a * 32;
  s16x8 qfA = *reinterpret_cast<const s16x8*>(qb + (bN + qbase + lc) * RCH + g * 8);
  s16x8 qfB = *reinterpret_cast<const s16x8*>(qb + (bN + qbase + 16 + lc) * RCH + g * 8);

  // staging: thread covers ch=(t>>3)+32i, LDS granule gr=t&7 (linear dest);
  // source granule pre-swizzled; granules 0-3 = stream0, 4-7 = stream1.
  int chb = t >> 3, gr = t & 7;
  int gsw = gr ^ (chb & 7);
  int koff = (gsw < 4) ? (gsw * 8) : (HALFK + (gsw - 4) * 8);
  const unsigned short* vsrc = vbase + (size_t)chb * NPIX + koff;

  // K pre-permuted rows
  int krb = 8 * (lc >> 2) + (lc & 3);
  int kO  = s * HALFK + krb;

  // PV read byte offset within a 128B row (this wave's stream granules)
  unsigned int swz = (lc & 7) << 4;
  int vrS = (s * 64 + g * 16) ^ swz;

  // ones B-operand for lsum MFMA (bf16 1.0 = 0x3F80)
  s16x8 ones;
  #pragma unroll
  for (int i = 0; i < 8; ++i) ones[i] = (short)0x3F80;

  f32x4 o[2][16];
  #pragma unroll
  for (int qh = 0; qh < 2; ++qh)
    #pragma unroll
    for (int cc = 0; cc < 16; ++cc) o[qh][cc] = zero;
  f32x4 ols[2];
  ols[0] = zero; ols[1] = zero;
  float m = 0.f;            // valid lower bound: relu'd q,k => S >= 0
  f32x4 mneg = zero;        // splat(-m)

  // ---- prologue: stage iter 0, load K subtile 0 ----
  #pragma unroll
  for (int i = 0; i < 8; ++i)
    gload_lds16(vsrc + (size_t)i * 32 * NPIX,
                (char*)&Vlds[0][0] + i * 4096 + t * 16);
  s16x8 kf0 = *reinterpret_cast<const s16x8*>(kbase + (size_t)(kO + 0) * RCH + g * 8);
  s16x8 kf1 = *reinterpret_cast<const s16x8*>(kbase + (size_t)(kO + 4) * RCH + g * 8);
  __syncthreads();

  for (int it = 0; it < NIT; ++it) {
    int p = it & 1;
    int kv = it * TK;
    bool nx = (it + 1) < NIT;

    // stage next iteration's subtiles (both streams) into the other buffer
    if (nx) {
      #pragma unroll
      for (int i = 0; i < 8; ++i)
        gload_lds16(vsrc + kv + TK + (size_t)i * 32 * NPIX,
                    (char*)&Vlds[p ^ 1][0] + i * 4096 + t * 16);
    }

    // ---- QK^T (C = -m splat: S arrives pre-shifted) ----
    f32x4 sA0 = __builtin_amdgcn_mfma_f32_16x16x32_bf16(kf0, qfA, mneg, 0, 0, 0);
    f32x4 sA1 = __builtin_amdgcn_mfma_f32_16x16x32_bf16(kf1, qfA, mneg, 0, 0, 0);
    f32x4 sB0 = __builtin_amdgcn_mfma_f32_16x16x32_bf16(kf0, qfB, mneg, 0, 0, 0);
    f32x4 sB1 = __builtin_amdgcn_mfma_f32_16x16x32_bf16(kf1, qfB, mneg, 0, 0, 0);

    // prefetch next K subtile
    if (nx) {
      kf0 = *reinterpret_cast<const s16x8*>(
          kbase + (size_t)(kO + kv + TK + 0) * RCH + g * 8);
      kf1 = *reinterpret_cast<const s16x8*>(
          kbase + (size_t)(kO + kv + TK + 4) * RCH + g * 8);
    }

    // ---- softmax max (shifted domain) ----
    float xA = fmaxf(fmaxf(sA0[0], sA0[1]), fmaxf(sA0[2], sA0[3]));
    float xB = fmaxf(fmaxf(sA1[0], sA1[1]), fmaxf(sA1[2], sA1[3]));
    float xC = fmaxf(fmaxf(sB0[0], sB0[1]), fmaxf(sB0[2], sB0[3]));
    float xD = fmaxf(fmaxf(sB1[0], sB1[1]), fmaxf(sB1[2], sB1[3]));
    float pmax = fmaxf(fmaxf(xA, xB), fmaxf(xC, xD));

    float sc = 1.f;
    int resc = !__all(pmax <= THR);
    if (resc) {
      #pragma unroll
      for (int off = 1; off <= 32; off <<= 1)
        pmax = fmaxf(pmax, __shfl_xor(pmax, off));
      float delta = fmaxf(pmax, 0.f);
      sc = exp2f(-delta);
      m += delta;
      f32x4 dd = {delta, delta, delta, delta};
      mneg -= dd;
      sA0 -= dd; sA1 -= dd; sB0 -= dd; sB1 -= dd;
    }

    // ---- exps + packed bf16 (cvt_pk), no per-element subtraction ----
    unsigned int pkA[4], pkB[4];
    pkA[0] = cvt_pk(exp2f(sA0[0]), exp2f(sA0[1]));
    pkA[1] = cvt_pk(exp2f(sA0[2]), exp2f(sA0[3]));
    pkA[2] = cvt_pk(exp2f(sA1[0]), exp2f(sA1[1]));
    pkA[3] = cvt_pk(exp2f(sA1[2]), exp2f(sA1[3]));
    pkB[0] = cvt_pk(exp2f(sB0[0]), exp2f(sB0[1]));
    pkB[1] = cvt_pk(exp2f(sB0[2]), exp2f(sB0[3]));
    pkB[2] = cvt_pk(exp2f(sB1[0]), exp2f(sB1[1]));
    pkB[3] = cvt_pk(exp2f(sB1[2]), exp2f(sB1[3]));

    if (resc) {
      #pragma unroll
      for (int qh = 0; qh < 2; ++qh) {
        #pragma unroll
        for (int cc = 0; cc < 16; ++cc)
          #pragma unroll
          for (int r = 0; r < 4; ++r) o[qh][cc][r] *= sc;
        #pragma unroll
        for (int r = 0; r < 4; ++r) ols[qh][r] *= sc;
      }
    }

    // ---- PV: one V fragment feeds both q-groups; +lsum MFMA vs ones ----
    u32x4 uA = {pkA[0], pkA[1], pkA[2], pkA[3]};
    u32x4 uB = {pkB[0], pkB[1], pkB[2], pkB[3]};
    s16x8 paA = __builtin_bit_cast(s16x8, uA);
    s16x8 paB = __builtin_bit_cast(s16x8, uB);
    const char* pb = (const char*)&Vlds[p][0] + lc * 128 + vrS;
    __builtin_amdgcn_s_setprio(1);
    ols[0] = __builtin_amdgcn_mfma_f32_16x16x32_bf16(paA, ones, ols[0], 0, 0, 0);
    ols[1] = __builtin_amdgcn_mfma_f32_16x16x32_bf16(paB, ones, ols[1], 0, 0, 0);
    #pragma unroll
    for (int cc = 0; cc < 16; ++cc) {
      s16x8 vb = *reinterpret_cast<const s16x8*>(pb + cc * 2048);
      o[0][cc] = __builtin_amdgcn_mfma_f32_16x16x32_bf16(paA, vb, o[0][cc], 0, 0, 0);
      o[1][cc] = __builtin_amdgcn_mfma_f32_16x16x32_bf16(paB, vb, o[1][cc], 0, 0, 0);
    }
    __builtin_amdgcn_s_setprio(0);

    __syncthreads();
  }

  // ---- merge prep: donor publishes per-q lsum (layout q = 4g+r) + m ----
  if (s == 1) {
    if (lc == 0) {
      *reinterpret_cast<f32x4*>(&mergeLS[a][4 * g])      = ols[0];
      *reinterpret_cast<f32x4*>(&mergeLS[a][16 + 4 * g]) = ols[1];
    }
    if (l == 0) mLds[a] = m;
  }
  __syncthreads();   // all PV done -> Vlds reusable as merge buffer

  float* mrg = (float*)&Vlds[0][0];   // 2 donors x 8192 floats
  if (s == 1) {
    float* base = mrg + a * 8192 + l * 128;
    #pragma unroll
    for (int qh = 0; qh < 2; ++qh)
      #pragma unroll
      for (int cc = 0; cc < 16; ++cc) {
        int idx = qh * 16 + cc;
        *reinterpret_cast<f32x4*>(base + ((idx + l) & 31) * 4) = o[qh][cc];
      }
  }
  __syncthreads();
  if (s == 0) {
    float mB = mLds[a];
    float mT = fmaxf(m, mB);
    float sAc = exp2f(m - mT), sBc = exp2f(mB - mT);
    const float* base = mrg + a * 8192 + l * 128;
    #pragma unroll
    for (int qh = 0; qh < 2; ++qh) {
      f32x4 lB4 = *reinterpret_cast<const f32x4*>(&mergeLS[a][qh * 16 + 4 * g]);
      f32x4 rl;
      #pragma unroll
      for (int r = 0; r < 4; ++r)
        rl[r] = 1.0f / (ols[qh][r] * sAc + lB4[r] * sBc);
      #pragma unroll
      for (int cc = 0; cc < 16; ++cc) {
        int idx = qh * 16 + cc;
        f32x4 ob = *reinterpret_cast<const f32x4*>(base + ((idx + l) & 31) * 4);
        #pragma unroll
        for (int r = 0; r < 4; ++r) {
          size_t row = bN + qbase + qh * 16 + 4 * g + r;
          size_t oi = row * CCH + cc * 16 + lc;
          out[oi] = (o[qh][cc][r] * sAc + ob[r] * sBc) * rl[r] + x[oi];
        }
      }
    }
  }
}

// ---------------------------------------------------------------------------
extern "C" void kernel_launch(void* const* d_in, const int* in_sizes, int n_in,
                              void* d_out, int out_size, void* d_ws, size_t ws_size,
                              hipStream_t stream) {
  const float* x  = (const float*)d_in[0];
  const float* wq = (const float*)d_in[1];
  const float* bq = (const float*)d_in[2];
  const float* wk = (const float*)d_in[3];
  const float* bk = (const float*)d_in[4];
  const float* wv = (const float*)d_in[5];
  const float* bv = (const float*)d_in[6];
  float* out = (float*)d_out;

  unsigned short* ws = (unsigned short*)d_ws;
  unsigned short* qb = ws;                   // 8*4096*32  = 1,048,576
  unsigned short* kb = qb + 1048576;         // 1,048,576
  unsigned short* vT = kb + 1048576;         // 8*256*4096 = 8,388,608

  proj_kernel<<<dim3(2560), dim3(256), 0, stream>>>(x, wq, wk, wv, bq, bk, bv,
                                                    qb, kb, vT);
  attn_kernel<<<dim3(512), dim3(256), 0, stream>>>(qb, kb, vT, x, out);
}